// Round 1
// baseline (4586.031 us; speedup 1.0000x reference)
//
#include <hip/hip_runtime.h>

typedef unsigned short u16;
typedef unsigned int u32;

#define N_NODES 200000
#define M_PAD   200064   // 128 * 1563
#define NE      3200000
#define NG      8192
#define TILE    128
#define BK      32
#define LDSTR   40       // 32 + 8 pad, keeps 16B alignment

typedef short s16x8 __attribute__((ext_vector_type(8)));
typedef float f32x4 __attribute__((ext_vector_type(4)));

__device__ __forceinline__ float bf2f(u16 u) {
    union { float f; u32 i; } x; x.i = ((u32)u) << 16; return x.f;
}
__device__ __forceinline__ u16 f2bf(float f) {
    union { float f; u32 i; } x; x.f = f;
    u32 r = (x.i + 0x7fffu + ((x.i >> 16) & 1u)) >> 16;
    return (u16)r;
}

// ---------------- degree / CSR build ----------------
__global__ void count_k(const int* __restrict__ col, int* __restrict__ deg, int e) {
    int i = blockIdx.x * 256 + threadIdx.x;
    if (i < e) atomicAdd(&deg[col[i]], 1);
}

__global__ void scan1_k(const int* __restrict__ deg, int* __restrict__ local,
                        int* __restrict__ bsums, int n) {
    __shared__ int s[256];
    int i = blockIdx.x * 256 + threadIdx.x;
    int v = (i < n) ? deg[i] : 0;
    s[threadIdx.x] = v;
    __syncthreads();
    for (int off = 1; off < 256; off <<= 1) {
        int t = (threadIdx.x >= off) ? s[threadIdx.x - off] : 0;
        __syncthreads();
        s[threadIdx.x] += t;
        __syncthreads();
    }
    if (i < n) local[i] = s[threadIdx.x] - v;  // exclusive
    if (threadIdx.x == 255) bsums[blockIdx.x] = s[255];
}

__global__ void scan2_k(int* __restrict__ bsums, int nb) {
    __shared__ int s[1024];
    int v = (threadIdx.x < nb) ? bsums[threadIdx.x] : 0;
    s[threadIdx.x] = v;
    __syncthreads();
    for (int off = 1; off < 1024; off <<= 1) {
        int t = (threadIdx.x >= off) ? s[threadIdx.x - off] : 0;
        __syncthreads();
        s[threadIdx.x] += t;
        __syncthreads();
    }
    if (threadIdx.x < nb) bsums[threadIdx.x] = s[threadIdx.x] - v;  // exclusive
}

__global__ void scan3_k(int* __restrict__ offsets, const int* __restrict__ bsums,
                        int* __restrict__ cursor, int n, int total) {
    int i = blockIdx.x * 256 + threadIdx.x;
    if (i < n) {
        int o = offsets[i] + bsums[i >> 8];
        offsets[i] = o;
        cursor[i] = o;
    }
    if (i == 0) offsets[n] = total;
}

__global__ void dinv_k(const int* __restrict__ deg, float* __restrict__ dinv,
                       int n, int npad) {
    int i = blockIdx.x * 256 + threadIdx.x;
    if (i < npad) dinv[i] = (i < n) ? rsqrtf((float)(deg[i] + 1)) : 0.f;
}

__global__ void fill_k(const int* __restrict__ row, const int* __restrict__ col,
                       int* __restrict__ cursor, int* __restrict__ csr, int e) {
    int i = blockIdx.x * 256 + threadIdx.x;
    if (i < e) {
        int p = atomicAdd(&cursor[col[i]], 1);
        csr[p] = row[i];
    }
}

// ---------------- fp32 -> bf16 (with zero-pad) ----------------
__global__ void f2b_pad_k(const float* __restrict__ x, u16* __restrict__ out,
                          int n, int ntot) {
    int i = blockIdx.x * 256 + threadIdx.x;
    if (i < ntot) out[i] = (i < n) ? f2bf(x[i]) : (u16)0;
}

// ---------------- weight transpose (fp32 [K,N] -> bf16 [N,K]) ----------------
struct WtArgs {
    const float* src[9];
    u16* dst[9];
    int K[9];
    int N[9];
};
__global__ void wt_k(WtArgs a) {
    int wi = blockIdx.y;
    int K = a.K[wi], N = a.N[wi];
    int idx = blockIdx.x * 256 + threadIdx.x;
    if (idx < K * N) {
        int k = idx / N, n = idx % N;
        a.dst[wi][n * K + k] = f2bf(a.src[wi][idx]);
    }
}

// ---------------- GEMM: C[M,N] = transform(A)[M,K] @ Wt[N,K]^T ----------------
// IN_MODE: 0 = raw bf16; 1 = relu(x + p0[kcol]); 2 = x*p0[kcol] + p1[kcol]
// OUT_MODE: 0 = bf16 acc*rowscale[row]; 1 = bf16 relu(acc + outb[col]); 2 = f32 acc + outb[col]
template<int IN_MODE, int OUT_MODE>
__global__ void __launch_bounds__(256) gemm_k(
    const u16* __restrict__ A, const u16* __restrict__ Bt, void* __restrict__ Cv,
    int K, int ldc,
    const float* __restrict__ p0, const float* __restrict__ p1,
    const float* __restrict__ rowscale, const float* __restrict__ outb)
{
    __shared__ u16 As[TILE * LDSTR];
    __shared__ u16 Bs[TILE * LDSTR];
    const int tid = threadIdx.x;
    const int lane = tid & 63;
    const int wid = tid >> 6;
    const int wm = wid & 1, wn = wid >> 1;
    const int bm0 = blockIdx.x * TILE;
    const int bn0 = blockIdx.y * TILE;

    f32x4 acc[4][4] = {};

    for (int kt = 0; kt < K; kt += BK) {
        #pragma unroll
        for (int it = 0; it < 2; ++it) {
            int idx = it * 256 + tid;
            int row = idx >> 2, cg = (idx & 3) << 3;
            const u16* srcA = A + (long)(bm0 + row) * K + kt + cg;
            uint4 va = *(const uint4*)srcA;
            if (IN_MODE != 0) {
                u16* h = (u16*)&va;
                #pragma unroll
                for (int j = 0; j < 8; ++j) {
                    float f = bf2f(h[j]);
                    int c = kt + cg + j;
                    if (IN_MODE == 1) f = fmaxf(f + p0[c], 0.f);
                    else               f = f * p0[c] + p1[c];
                    h[j] = f2bf(f);
                }
            }
            *(uint4*)&As[row * LDSTR + cg] = va;
            const u16* srcB = Bt + (long)(bn0 + row) * K + kt + cg;
            *(uint4*)&Bs[row * LDSTR + cg] = *(const uint4*)srcB;
        }
        __syncthreads();

        s16x8 af[4], bfr[4];
        int koff = (lane >> 4) << 3;
        #pragma unroll
        for (int i = 0; i < 4; ++i) {
            int rA = wm * 64 + i * 16 + (lane & 15);
            af[i] = *(const s16x8*)&As[rA * LDSTR + koff];
            int rB = wn * 64 + i * 16 + (lane & 15);
            bfr[i] = *(const s16x8*)&Bs[rB * LDSTR + koff];
        }
        #pragma unroll
        for (int i = 0; i < 4; ++i)
            #pragma unroll
            for (int j = 0; j < 4; ++j)
                acc[i][j] = __builtin_amdgcn_mfma_f32_16x16x32_bf16(af[i], bfr[j], acc[i][j], 0, 0, 0);
        __syncthreads();
    }

    // epilogue: D row = (lane>>4)*4 + r, col = lane&15  (within 16x16 tile)
    #pragma unroll
    for (int i = 0; i < 4; ++i) {
        int rbase = wm * 64 + i * 16 + ((lane >> 4) << 2);
        #pragma unroll
        for (int j = 0; j < 4; ++j) {
            int col = bn0 + wn * 64 + j * 16 + (lane & 15);
            #pragma unroll
            for (int r = 0; r < 4; ++r) {
                long row = bm0 + rbase + r;
                float v = acc[i][j][r];
                if (OUT_MODE == 0) {
                    v *= rowscale[row];
                    ((u16*)Cv)[row * ldc + col] = f2bf(v);
                } else if (OUT_MODE == 1) {
                    v = fmaxf(v + outb[col], 0.f);
                    ((u16*)Cv)[row * ldc + col] = f2bf(v);
                } else {
                    ((float*)Cv)[row * ldc + col] = v + outb[col];
                }
            }
        }
    }
}

// ---------------- aggregation: out[c] = dinv[c] * (hs[c] + sum_{nbr} hs[nbr]) ----------------
template<int DIM>
__global__ void __launch_bounds__(256) agg_k(
    const u16* __restrict__ hs, u16* __restrict__ out,
    const float* __restrict__ dinv, const int* __restrict__ offs,
    const int* __restrict__ rows, int n)
{
    constexpr int VPL = DIM / 64;
    int node = (blockIdx.x << 2) + (threadIdx.x >> 6);
    if (node >= n) return;
    int lane = threadIdx.x & 63;
    const u16* self = hs + (size_t)node * DIM + lane * VPL;

    float acc[VPL];
    {
        u16 tmp[VPL];
        if constexpr (VPL == 4) *(uint2*)tmp = *(const uint2*)self;
        else                    *(u32*)tmp  = *(const u32*)self;
        #pragma unroll
        for (int v = 0; v < VPL; ++v) acc[v] = bf2f(tmp[v]);
    }
    int b = offs[node], e = offs[node + 1];
    int j = b;
    for (; j + 1 < e; j += 2) {
        int r0 = rows[j], r1 = rows[j + 1];
        const u16* q0 = hs + (size_t)r0 * DIM + lane * VPL;
        const u16* q1 = hs + (size_t)r1 * DIM + lane * VPL;
        u16 t0[VPL], t1[VPL];
        if constexpr (VPL == 4) { *(uint2*)t0 = *(const uint2*)q0; *(uint2*)t1 = *(const uint2*)q1; }
        else                    { *(u32*)t0  = *(const u32*)q0;  *(u32*)t1  = *(const u32*)q1; }
        #pragma unroll
        for (int v = 0; v < VPL; ++v) acc[v] += bf2f(t0[v]) + bf2f(t1[v]);
    }
    if (j < e) {
        int r0 = rows[j];
        const u16* q0 = hs + (size_t)r0 * DIM + lane * VPL;
        u16 t0[VPL];
        if constexpr (VPL == 4) *(uint2*)t0 = *(const uint2*)q0;
        else                    *(u32*)t0  = *(const u32*)q0;
        #pragma unroll
        for (int v = 0; v < VPL; ++v) acc[v] += bf2f(t0[v]);
    }
    float dv = dinv[node];
    u16 o[VPL];
    #pragma unroll
    for (int v = 0; v < VPL; ++v) o[v] = f2bf(acc[v] * dv);
    u16* op = out + (size_t)node * DIM + lane * VPL;
    if constexpr (VPL == 4) *(uint2*)op = *(uint2*)o;
    else                    *(u32*)op  = *(u32*)o;
}

// ---------------- mean pool: relu(agg + b) summed by graph ----------------
__global__ void pool_k(const u16* __restrict__ agg, const float* __restrict__ b4,
                       const int* __restrict__ batch, float* __restrict__ pool,
                       int* __restrict__ cnt, int n) {
    int t = blockIdx.x * 256 + threadIdx.x;
    if (t >= n * 32) return;
    int node = t >> 5, q = t & 31;
    int g = batch[node];
    uint2 u = *(const uint2*)(agg + (size_t)node * 128 + q * 4);
    u16* h = (u16*)&u;
    #pragma unroll
    for (int i = 0; i < 4; ++i) {
        float v = fmaxf(bf2f(h[i]) + b4[q * 4 + i], 0.f);
        atomicAdd(&pool[g * 128 + q * 4 + i], v);
    }
    if (q == 0) atomicAdd(&cnt[g], 1);
}

__global__ void finpool_k(const float* __restrict__ pool, const int* __restrict__ cnt,
                          u16* __restrict__ dst) {
    int t = blockIdx.x * 256 + threadIdx.x;  // 0 .. NG*128
    int g = t >> 7, col = t & 127;
    float c = fmaxf((float)cnt[g], 1.f);
    dst[g * 512 + col] = f2bf(pool[t] / c);
}

// ---------------- batch-norm stats ----------------
__global__ void colred_k(const u16* __restrict__ h, float* __restrict__ sum,
                         float* __restrict__ sumsq, int N, int rowsPer) {
    int col = threadIdx.x;  // N threads
    long r0 = (long)blockIdx.x * rowsPer;
    float s = 0.f, s2 = 0.f;
    for (int r = 0; r < rowsPer; ++r) {
        float v = bf2f(h[(r0 + r) * N + col]);
        s += v; s2 += v * v;
    }
    atomicAdd(&sum[col], s);
    atomicAdd(&sumsq[col], s2);
}

__global__ void bnfin_k(const float* __restrict__ sum, const float* __restrict__ sumsq,
                        const float* __restrict__ g, const float* __restrict__ be,
                        float* __restrict__ scale, float* __restrict__ shift, int N) {
    int i = threadIdx.x;
    if (i >= N) return;
    float mu = sum[i] * (1.f / 8192.f);
    float var = sumsq[i] * (1.f / 8192.f) - mu * mu;
    float sc = g[i] * rsqrtf(var + 1e-5f);
    scale[i] = sc;
    shift[i] = be[i] - mu * sc;
}

// ---------------- host ----------------
extern "C" void kernel_launch(void* const* d_in, const int* in_sizes, int n_in,
                              void* d_out, int out_size, void* d_ws, size_t ws_size,
                              hipStream_t stream) {
    const float* x1 = (const float*)d_in[0];
    const float* x2 = (const float*)d_in[1];
    const int* ei1 = (const int*)d_in[2];
    const int* ei2 = (const int*)d_in[3];
    const int* bt1 = (const int*)d_in[4];
    const int* bt2 = (const int*)d_in[5];
    const float* nt1 = (const float*)d_in[6];
    const float* nt2 = (const float*)d_in[7];
    const float* Wc1 = (const float*)d_in[8];  const float* bc1 = (const float*)d_in[9];
    const float* Wc2 = (const float*)d_in[10]; const float* bc2 = (const float*)d_in[11];
    const float* Wc3 = (const float*)d_in[12]; const float* bc3 = (const float*)d_in[13];
    const float* Wc4 = (const float*)d_in[14]; const float* bc4 = (const float*)d_in[15];
    const float* Wn1 = (const float*)d_in[16]; const float* bn1 = (const float*)d_in[17];
    const float* Wn2 = (const float*)d_in[18]; const float* bn2 = (const float*)d_in[19];
    const float* Wf1 = (const float*)d_in[20]; const float* bf1 = (const float*)d_in[21];
    const float* g1  = (const float*)d_in[22]; const float* be1 = (const float*)d_in[23];
    const float* Wf2 = (const float*)d_in[24]; const float* bf2 = (const float*)d_in[25];
    const float* g2  = (const float*)d_in[26]; const float* be2 = (const float*)d_in[27];
    const float* Wf3 = (const float*)d_in[28]; const float* bf3 = (const float*)d_in[29];

    char* base = (char*)d_ws;
    size_t off = 0;
    auto alloc = [&](size_t bytes) -> char* {
        char* r = base + off;
        off = (off + bytes + 255) & ~(size_t)255;
        return r;
    };
    u16*   bufA    = (u16*)  alloc((size_t)M_PAD * 256 * 2);
    u16*   bufB    = (u16*)  alloc((size_t)M_PAD * 256 * 2);
    int*   csr     = (int*)  alloc((size_t)NE * 4);
    int*   offsets = (int*)  alloc((size_t)(N_NODES + 1) * 4);
    int*   cursor  = (int*)  alloc((size_t)N_NODES * 4);
    int*   deg     = (int*)  alloc((size_t)N_NODES * 4);
    float* dinv    = (float*)alloc((size_t)M_PAD * 4);
    int*   bsums   = (int*)  alloc(4096);
    u16*   wt      = (u16*)  alloc(442368 * 2);
    u16*   cbuf    = (u16*)  alloc((size_t)NG * 512 * 2);
    u16*   nh      = (u16*)  alloc((size_t)NG * 256 * 2);
    u16*   notesA  = (u16*)  alloc((size_t)NG * 128 * 2);
    u16*   h1      = (u16*)  alloc((size_t)NG * 256 * 2);
    u16*   h2      = (u16*)  alloc((size_t)NG * 128 * 2);
    float* pool    = (float*)alloc((size_t)NG * 128 * 4);
    int*   cnt     = (int*)  alloc((size_t)NG * 4);
    float* colsum  = (float*)alloc(1024);
    float* colsumsq= (float*)alloc(1024);
    float* scale   = (float*)alloc(1024);
    float* shift   = (float*)alloc(1024);
    if (off > ws_size) return;  // insufficient workspace — bail

    // weight transposes: offsets into wt (elements)
    u16* wc1t = wt;            u16* wc2t = wt + 32768;  u16* wc3t = wt + 98304;
    u16* wc4t = wt + 163840;   u16* wn1t = wt + 196608; u16* wn2t = wt + 229376;
    u16* wf1t = wt + 262144;   u16* wf2t = wt + 393216; u16* wf3t = wt + 425984;
    {
        WtArgs wa;
        const float* s[9] = {Wc1, Wc2, Wc3, Wc4, Wn1, Wn2, Wf1, Wf2, Wf3};
        u16* dsts[9]      = {wc1t, wc2t, wc3t, wc4t, wn1t, wn2t, wf1t, wf2t, wf3t};
        int Ks[9] = {128, 256, 256, 256, 128, 256, 512, 256, 128};
        int Ns[9] = {256, 256, 256, 128, 256, 128, 256, 128, 128};
        for (int i = 0; i < 9; ++i) { wa.src[i] = s[i]; wa.dst[i] = dsts[i]; wa.K[i] = Ks[i]; wa.N[i] = Ns[i]; }
        hipLaunchKernelGGL(wt_k, dim3(512, 9), dim3(256), 0, stream, wa);
    }

    for (int t = 0; t < 2; ++t) {
        const float* x   = t ? x2 : x1;
        const int*   ei  = t ? ei2 : ei1;
        const int*   bat = t ? bt2 : bt1;

        hipMemsetAsync(deg, 0, (size_t)N_NODES * 4, stream);
        count_k<<<NE / 256, 256, 0, stream>>>(ei + NE, deg, NE);
        scan1_k<<<782, 256, 0, stream>>>(deg, offsets, bsums, N_NODES);
        scan2_k<<<1, 1024, 0, stream>>>(bsums, 782);
        scan3_k<<<782, 256, 0, stream>>>(offsets, bsums, cursor, N_NODES, NE);
        dinv_k<<<782, 256, 0, stream>>>(deg, dinv, N_NODES, M_PAD);
        fill_k<<<NE / 256, 256, 0, stream>>>(ei, ei + NE, cursor, csr, NE);
        f2b_pad_k<<<(M_PAD * 128) / 256, 256, 0, stream>>>(x, bufA, N_NODES * 128, M_PAD * 128);

        // layer 1: K=128 N=256
        gemm_k<0, 0><<<dim3(M_PAD / 128, 2), 256, 0, stream>>>(bufA, wc1t, bufB, 128, 256,
                                                               nullptr, nullptr, dinv, nullptr);
        agg_k<256><<<N_NODES / 4, 256, 0, stream>>>(bufB, bufA, dinv, offsets, csr, N_NODES);
        // layer 2: K=256 N=256, A = relu(agg + bc1)
        gemm_k<1, 0><<<dim3(M_PAD / 128, 2), 256, 0, stream>>>(bufA, wc2t, bufB, 256, 256,
                                                               bc1, nullptr, dinv, nullptr);
        agg_k<256><<<N_NODES / 4, 256, 0, stream>>>(bufB, bufA, dinv, offsets, csr, N_NODES);
        // layer 3
        gemm_k<1, 0><<<dim3(M_PAD / 128, 2), 256, 0, stream>>>(bufA, wc3t, bufB, 256, 256,
                                                               bc2, nullptr, dinv, nullptr);
        agg_k<256><<<N_NODES / 4, 256, 0, stream>>>(bufB, bufA, dinv, offsets, csr, N_NODES);
        // layer 4: K=256 N=128
        gemm_k<1, 0><<<dim3(M_PAD / 128, 1), 256, 0, stream>>>(bufA, wc4t, bufB, 256, 128,
                                                               bc3, nullptr, dinv, nullptr);
        agg_k<128><<<N_NODES / 4, 256, 0, stream>>>(bufB, bufA, dinv, offsets, csr, N_NODES);

        // mean pool of relu(agg4 + bc4)
        hipMemsetAsync(pool, 0, (size_t)NG * 128 * 4 + (size_t)NG * 4, stream);  // pool + cnt contiguous
        pool_k<<<(N_NODES * 32) / 256, 256, 0, stream>>>(bufA, bc4, bat, pool, cnt, N_NODES);
        finpool_k<<<(NG * 128) / 256, 256, 0, stream>>>(pool, cnt, cbuf + t * 128);
    }

    // notes MLPs -> cbuf cols 256..511
    for (int t = 0; t < 2; ++t) {
        const float* nt = t ? nt2 : nt1;
        f2b_pad_k<<<(NG * 128) / 256, 256, 0, stream>>>(nt, notesA, NG * 128, NG * 128);
        gemm_k<0, 1><<<dim3(NG / 128, 2), 256, 0, stream>>>(notesA, wn1t, nh, 128, 256,
                                                            nullptr, nullptr, nullptr, bn1);
        gemm_k<0, 1><<<dim3(NG / 128, 1), 256, 0, stream>>>(nh, wn2t, cbuf + 256 + t * 128, 256, 512,
                                                            nullptr, nullptr, nullptr, bn2);
    }

    // fusion head
    gemm_k<0, 1><<<dim3(NG / 128, 2), 256, 0, stream>>>(cbuf, wf1t, h1, 512, 256,
                                                        nullptr, nullptr, nullptr, bf1);
    hipMemsetAsync(colsum, 0, 2048, stream);  // colsum + colsumsq contiguous
    colred_k<<<256, 256, 0, stream>>>(h1, colsum, colsumsq, 256, 32);
    bnfin_k<<<1, 256, 0, stream>>>(colsum, colsumsq, g1, be1, scale, shift, 256);
    gemm_k<2, 1><<<dim3(NG / 128, 1), 256, 0, stream>>>(h1, wf2t, h2, 256, 128,
                                                        scale, shift, nullptr, bf2);
    hipMemsetAsync(colsum, 0, 2048, stream);
    colred_k<<<128, 128, 0, stream>>>(h2, colsum, colsumsq, 128, 64);
    bnfin_k<<<1, 128, 0, stream>>>(colsum, colsumsq, g2, be2, scale, shift, 128);
    gemm_k<2, 2><<<dim3(NG / 128, 1), 256, 0, stream>>>(h2, wf3t, d_out, 128, 128,
                                                        scale, shift, nullptr, bf3);
}

// Round 2
// 3786.707 us; speedup vs baseline: 1.2111x; 1.2111x over previous
//
#include <hip/hip_runtime.h>

typedef unsigned short u16;
typedef unsigned int u32;

#define N_NODES 200000
#define M_PAD   200064   // 128 * 1563
#define NE      3200000
#define NG      8192
#define TILE    128
#define BK      32
#define LDSTR   40       // 32 + 8 pad, keeps 16B alignment

typedef short s16x8 __attribute__((ext_vector_type(8)));
typedef float f32x4 __attribute__((ext_vector_type(4)));

__device__ __forceinline__ float bf2f(u16 u) {
    union { float f; u32 i; } x; x.i = ((u32)u) << 16; return x.f;
}
__device__ __forceinline__ u16 f2bf(float f) {
    union { float f; u32 i; } x; x.f = f;
    u32 r = (x.i + 0x7fffu + ((x.i >> 16) & 1u)) >> 16;
    return (u16)r;
}

// ---------------- degree / CSR build ----------------
__global__ void count_k(const int* __restrict__ col, int* __restrict__ deg, int e) {
    int i = blockIdx.x * 256 + threadIdx.x;
    if (i < e) atomicAdd(&deg[col[i]], 1);
}

__global__ void scan1_k(const int* __restrict__ deg, int* __restrict__ local,
                        int* __restrict__ bsums, int n) {
    __shared__ int s[256];
    int i = blockIdx.x * 256 + threadIdx.x;
    int v = (i < n) ? deg[i] : 0;
    s[threadIdx.x] = v;
    __syncthreads();
    for (int off = 1; off < 256; off <<= 1) {
        int t = (threadIdx.x >= off) ? s[threadIdx.x - off] : 0;
        __syncthreads();
        s[threadIdx.x] += t;
        __syncthreads();
    }
    if (i < n) local[i] = s[threadIdx.x] - v;  // exclusive
    if (threadIdx.x == 255) bsums[blockIdx.x] = s[255];
}

__global__ void scan2_k(int* __restrict__ bsums, int nb) {
    __shared__ int s[1024];
    int v = (threadIdx.x < nb) ? bsums[threadIdx.x] : 0;
    s[threadIdx.x] = v;
    __syncthreads();
    for (int off = 1; off < 1024; off <<= 1) {
        int t = (threadIdx.x >= off) ? s[threadIdx.x - off] : 0;
        __syncthreads();
        s[threadIdx.x] += t;
        __syncthreads();
    }
    if (threadIdx.x < nb) bsums[threadIdx.x] = s[threadIdx.x] - v;  // exclusive
}

__global__ void scan3_k(int* __restrict__ offsets, const int* __restrict__ bsums,
                        int* __restrict__ cursor, int n, int total) {
    int i = blockIdx.x * 256 + threadIdx.x;
    if (i < n) {
        int o = offsets[i] + bsums[i >> 8];
        offsets[i] = o;
        cursor[i] = o;
    }
    if (i == 0) offsets[n] = total;
}

__global__ void dinv_k(const int* __restrict__ deg, float* __restrict__ dinv,
                       int n, int npad) {
    int i = blockIdx.x * 256 + threadIdx.x;
    if (i < npad) dinv[i] = (i < n) ? rsqrtf((float)(deg[i] + 1)) : 0.f;
}

__global__ void fill_k(const int* __restrict__ row, const int* __restrict__ col,
                       int* __restrict__ cursor, int* __restrict__ csr, int e) {
    int i = blockIdx.x * 256 + threadIdx.x;
    if (i < e) {
        int p = atomicAdd(&cursor[col[i]], 1);
        csr[p] = row[i];
    }
}

// ---------------- graph segment starts (batch is sorted) ----------------
__global__ void gstart_k(const int* __restrict__ batch, int* __restrict__ gstart,
                         int n, int g) {
    int i = blockIdx.x * 256 + threadIdx.x;
    if (i > g) return;
    if (i == g) { gstart[g] = n; return; }
    // lower_bound: first idx with batch[idx] >= i
    int lo = 0, hi = n;
    while (lo < hi) {
        int mid = (lo + hi) >> 1;
        if (batch[mid] < i) lo = mid + 1; else hi = mid;
    }
    gstart[i] = lo;
}

// ---------------- fp32 -> bf16 (with zero-pad) ----------------
__global__ void f2b_pad_k(const float* __restrict__ x, u16* __restrict__ out,
                          int n, int ntot) {
    int i = blockIdx.x * 256 + threadIdx.x;
    if (i < ntot) out[i] = (i < n) ? f2bf(x[i]) : (u16)0;
}

// ---------------- weight transpose (fp32 [K,N] -> bf16 [N,K]) ----------------
struct WtArgs {
    const float* src[9];
    u16* dst[9];
    int K[9];
    int N[9];
};
__global__ void wt_k(WtArgs a) {
    int wi = blockIdx.y;
    int K = a.K[wi], N = a.N[wi];
    int idx = blockIdx.x * 256 + threadIdx.x;
    if (idx < K * N) {
        int k = idx / N, n = idx % N;
        a.dst[wi][n * K + k] = f2bf(a.src[wi][idx]);
    }
}

// ---------------- GEMM: C[M,N] = transform(A)[M,K] @ Wt[N,K]^T ----------------
// IN_MODE: 0 = raw bf16; 1 = relu(x + p0[kcol]); 2 = x*p0[kcol] + p1[kcol]
// OUT_MODE: 0 = bf16 acc*rowscale[row]; 1 = bf16 relu(acc + outb[col]); 2 = f32 acc + outb[col]
template<int IN_MODE, int OUT_MODE>
__global__ void __launch_bounds__(256) gemm_k(
    const u16* __restrict__ A, const u16* __restrict__ Bt, void* __restrict__ Cv,
    int K, int ldc,
    const float* __restrict__ p0, const float* __restrict__ p1,
    const float* __restrict__ rowscale, const float* __restrict__ outb)
{
    __shared__ u16 As[TILE * LDSTR];
    __shared__ u16 Bs[TILE * LDSTR];
    const int tid = threadIdx.x;
    const int lane = tid & 63;
    const int wid = tid >> 6;
    const int wm = wid & 1, wn = wid >> 1;
    const int bm0 = blockIdx.x * TILE;
    const int bn0 = blockIdx.y * TILE;

    f32x4 acc[4][4] = {};

    for (int kt = 0; kt < K; kt += BK) {
        #pragma unroll
        for (int it = 0; it < 2; ++it) {
            int idx = it * 256 + tid;
            int row = idx >> 2, cg = (idx & 3) << 3;
            const u16* srcA = A + (long)(bm0 + row) * K + kt + cg;
            uint4 va = *(const uint4*)srcA;
            if (IN_MODE != 0) {
                u16* h = (u16*)&va;
                #pragma unroll
                for (int j = 0; j < 8; ++j) {
                    float f = bf2f(h[j]);
                    int c = kt + cg + j;
                    if (IN_MODE == 1) f = fmaxf(f + p0[c], 0.f);
                    else               f = f * p0[c] + p1[c];
                    h[j] = f2bf(f);
                }
            }
            *(uint4*)&As[row * LDSTR + cg] = va;
            const u16* srcB = Bt + (long)(bn0 + row) * K + kt + cg;
            *(uint4*)&Bs[row * LDSTR + cg] = *(const uint4*)srcB;
        }
        __syncthreads();

        s16x8 af[4], bfr[4];
        int koff = (lane >> 4) << 3;
        #pragma unroll
        for (int i = 0; i < 4; ++i) {
            int rA = wm * 64 + i * 16 + (lane & 15);
            af[i] = *(const s16x8*)&As[rA * LDSTR + koff];
            int rB = wn * 64 + i * 16 + (lane & 15);
            bfr[i] = *(const s16x8*)&Bs[rB * LDSTR + koff];
        }
        #pragma unroll
        for (int i = 0; i < 4; ++i)
            #pragma unroll
            for (int j = 0; j < 4; ++j)
                acc[i][j] = __builtin_amdgcn_mfma_f32_16x16x32_bf16(af[i], bfr[j], acc[i][j], 0, 0, 0);
        __syncthreads();
    }

    // epilogue: D row = (lane>>4)*4 + r, col = lane&15  (within 16x16 tile)
    #pragma unroll
    for (int i = 0; i < 4; ++i) {
        int rbase = wm * 64 + i * 16 + ((lane >> 4) << 2);
        #pragma unroll
        for (int j = 0; j < 4; ++j) {
            int col = bn0 + wn * 64 + j * 16 + (lane & 15);
            #pragma unroll
            for (int r = 0; r < 4; ++r) {
                long row = bm0 + rbase + r;
                float v = acc[i][j][r];
                if (OUT_MODE == 0) {
                    v *= rowscale[row];
                    ((u16*)Cv)[row * ldc + col] = f2bf(v);
                } else if (OUT_MODE == 1) {
                    v = fmaxf(v + outb[col], 0.f);
                    ((u16*)Cv)[row * ldc + col] = f2bf(v);
                } else {
                    ((float*)Cv)[row * ldc + col] = v + outb[col];
                }
            }
        }
    }
}

// ---------------- aggregation: out[c] = dinv[c] * (hs[c] + sum_{nbr} hs[nbr]) ----------------
template<int DIM>
__global__ void __launch_bounds__(256) agg_k(
    const u16* __restrict__ hs, u16* __restrict__ out,
    const float* __restrict__ dinv, const int* __restrict__ offs,
    const int* __restrict__ rows, int n)
{
    constexpr int VPL = DIM / 64;
    int node = (blockIdx.x << 2) + (threadIdx.x >> 6);
    if (node >= n) return;
    int lane = threadIdx.x & 63;
    const u16* self = hs + (size_t)node * DIM + lane * VPL;

    float acc[VPL];
    {
        u16 tmp[VPL];
        if constexpr (VPL == 4) *(uint2*)tmp = *(const uint2*)self;
        else                    *(u32*)tmp  = *(const u32*)self;
        #pragma unroll
        for (int v = 0; v < VPL; ++v) acc[v] = bf2f(tmp[v]);
    }
    int b = offs[node], e = offs[node + 1];
    int j = b;
    for (; j + 1 < e; j += 2) {
        int r0 = rows[j], r1 = rows[j + 1];
        const u16* q0 = hs + (size_t)r0 * DIM + lane * VPL;
        const u16* q1 = hs + (size_t)r1 * DIM + lane * VPL;
        u16 t0[VPL], t1[VPL];
        if constexpr (VPL == 4) { *(uint2*)t0 = *(const uint2*)q0; *(uint2*)t1 = *(const uint2*)q1; }
        else                    { *(u32*)t0  = *(const u32*)q0;  *(u32*)t1  = *(const u32*)q1; }
        #pragma unroll
        for (int v = 0; v < VPL; ++v) acc[v] += bf2f(t0[v]) + bf2f(t1[v]);
    }
    if (j < e) {
        int r0 = rows[j];
        const u16* q0 = hs + (size_t)r0 * DIM + lane * VPL;
        u16 t0[VPL];
        if constexpr (VPL == 4) *(uint2*)t0 = *(const uint2*)q0;
        else                    *(u32*)t0  = *(const u32*)q0;
        #pragma unroll
        for (int v = 0; v < VPL; ++v) acc[v] += bf2f(t0[v]);
    }
    float dv = dinv[node];
    u16 o[VPL];
    #pragma unroll
    for (int v = 0; v < VPL; ++v) o[v] = f2bf(acc[v] * dv);
    u16* op = out + (size_t)node * DIM + lane * VPL;
    if constexpr (VPL == 4) *(uint2*)op = *(uint2*)o;
    else                    *(u32*)op  = *(u32*)o;
}

// ---------------- segmented mean pool: one wave per graph (batch sorted) ----------------
// dst[g*512 + d] = mean over nodes in graph g of relu(agg[n][d] + b4[d])
__global__ void __launch_bounds__(256) pool2_k(
    const u16* __restrict__ agg, const float* __restrict__ b4,
    const int* __restrict__ gstart, u16* __restrict__ dst)
{
    int g = (blockIdx.x << 2) + (threadIdx.x >> 6);
    int lane = threadIdx.x & 63;
    int s = gstart[g], e = gstart[g + 1];
    float bias0 = b4[lane * 2], bias1 = b4[lane * 2 + 1];
    float a0 = 0.f, a1 = 0.f;
    for (int n = s; n < e; ++n) {
        u32 u = *(const u32*)(agg + (size_t)n * 128 + lane * 2);
        a0 += fmaxf(bf2f((u16)u) + bias0, 0.f);
        a1 += fmaxf(bf2f((u16)(u >> 16)) + bias1, 0.f);
    }
    float c = 1.f / fmaxf((float)(e - s), 1.f);
    dst[(size_t)g * 512 + lane * 2]     = f2bf(a0 * c);
    dst[(size_t)g * 512 + lane * 2 + 1] = f2bf(a1 * c);
}

// ---------------- batch-norm stats ----------------
__global__ void colred_k(const u16* __restrict__ h, float* __restrict__ sum,
                         float* __restrict__ sumsq, int N, int rowsPer) {
    int col = threadIdx.x;  // N threads
    long r0 = (long)blockIdx.x * rowsPer;
    float s = 0.f, s2 = 0.f;
    for (int r = 0; r < rowsPer; ++r) {
        float v = bf2f(h[(r0 + r) * N + col]);
        s += v; s2 += v * v;
    }
    atomicAdd(&sum[col], s);
    atomicAdd(&sumsq[col], s2);
}

__global__ void bnfin_k(const float* __restrict__ sum, const float* __restrict__ sumsq,
                        const float* __restrict__ g, const float* __restrict__ be,
                        float* __restrict__ scale, float* __restrict__ shift, int N) {
    int i = threadIdx.x;
    if (i >= N) return;
    float mu = sum[i] * (1.f / 8192.f);
    float var = sumsq[i] * (1.f / 8192.f) - mu * mu;
    float sc = g[i] * rsqrtf(var + 1e-5f);
    scale[i] = sc;
    shift[i] = be[i] - mu * sc;
}

// ---------------- host ----------------
extern "C" void kernel_launch(void* const* d_in, const int* in_sizes, int n_in,
                              void* d_out, int out_size, void* d_ws, size_t ws_size,
                              hipStream_t stream) {
    const float* x1 = (const float*)d_in[0];
    const float* x2 = (const float*)d_in[1];
    const int* ei1 = (const int*)d_in[2];
    const int* ei2 = (const int*)d_in[3];
    const int* bt1 = (const int*)d_in[4];
    const int* bt2 = (const int*)d_in[5];
    const float* nt1 = (const float*)d_in[6];
    const float* nt2 = (const float*)d_in[7];
    const float* Wc1 = (const float*)d_in[8];  const float* bc1 = (const float*)d_in[9];
    const float* Wc2 = (const float*)d_in[10]; const float* bc2 = (const float*)d_in[11];
    const float* Wc3 = (const float*)d_in[12]; const float* bc3 = (const float*)d_in[13];
    const float* Wc4 = (const float*)d_in[14]; const float* bc4 = (const float*)d_in[15];
    const float* Wn1 = (const float*)d_in[16]; const float* bn1 = (const float*)d_in[17];
    const float* Wn2 = (const float*)d_in[18]; const float* bn2 = (const float*)d_in[19];
    const float* Wf1 = (const float*)d_in[20]; const float* bf1 = (const float*)d_in[21];
    const float* g1  = (const float*)d_in[22]; const float* be1 = (const float*)d_in[23];
    const float* Wf2 = (const float*)d_in[24]; const float* bf2 = (const float*)d_in[25];
    const float* g2  = (const float*)d_in[26]; const float* be2 = (const float*)d_in[27];
    const float* Wf3 = (const float*)d_in[28]; const float* bf3 = (const float*)d_in[29];

    char* base = (char*)d_ws;
    size_t off = 0;
    auto alloc = [&](size_t bytes) -> char* {
        char* r = base + off;
        off = (off + bytes + 255) & ~(size_t)255;
        return r;
    };
    u16*   bufA    = (u16*)  alloc((size_t)M_PAD * 256 * 2);
    u16*   bufB    = (u16*)  alloc((size_t)M_PAD * 256 * 2);
    int*   csr     = (int*)  alloc((size_t)NE * 4);
    int*   offsets = (int*)  alloc((size_t)(N_NODES + 1) * 4);
    int*   cursor  = (int*)  alloc((size_t)N_NODES * 4);
    int*   deg     = (int*)  alloc((size_t)N_NODES * 4);
    float* dinv    = (float*)alloc((size_t)M_PAD * 4);
    int*   bsums   = (int*)  alloc(4096);
    int*   gstart  = (int*)  alloc((size_t)(NG + 1) * 4);
    u16*   wt      = (u16*)  alloc(442368 * 2);
    u16*   cbuf    = (u16*)  alloc((size_t)NG * 512 * 2);
    u16*   nh      = (u16*)  alloc((size_t)NG * 256 * 2);
    u16*   notesA  = (u16*)  alloc((size_t)NG * 128 * 2);
    u16*   h1      = (u16*)  alloc((size_t)NG * 256 * 2);
    u16*   h2      = (u16*)  alloc((size_t)NG * 128 * 2);
    float* colsum  = (float*)alloc(1024);
    float* colsumsq= (float*)alloc(1024);
    float* scale   = (float*)alloc(1024);
    float* shift   = (float*)alloc(1024);
    if (off > ws_size) return;  // insufficient workspace — bail

    // weight transposes: offsets into wt (elements)
    u16* wc1t = wt;            u16* wc2t = wt + 32768;  u16* wc3t = wt + 98304;
    u16* wc4t = wt + 163840;   u16* wn1t = wt + 196608; u16* wn2t = wt + 229376;
    u16* wf1t = wt + 262144;   u16* wf2t = wt + 393216; u16* wf3t = wt + 425984;
    {
        WtArgs wa;
        const float* s[9] = {Wc1, Wc2, Wc3, Wc4, Wn1, Wn2, Wf1, Wf2, Wf3};
        u16* dsts[9]      = {wc1t, wc2t, wc3t, wc4t, wn1t, wn2t, wf1t, wf2t, wf3t};
        int Ks[9] = {128, 256, 256, 256, 128, 256, 512, 256, 128};
        int Ns[9] = {256, 256, 256, 128, 256, 128, 256, 128, 128};
        for (int i = 0; i < 9; ++i) { wa.src[i] = s[i]; wa.dst[i] = dsts[i]; wa.K[i] = Ks[i]; wa.N[i] = Ns[i]; }
        hipLaunchKernelGGL(wt_k, dim3(512, 9), dim3(256), 0, stream, wa);
    }

    for (int t = 0; t < 2; ++t) {
        const float* x   = t ? x2 : x1;
        const int*   ei  = t ? ei2 : ei1;
        const int*   bat = t ? bt2 : bt1;

        hipMemsetAsync(deg, 0, (size_t)N_NODES * 4, stream);
        count_k<<<NE / 256, 256, 0, stream>>>(ei + NE, deg, NE);
        scan1_k<<<782, 256, 0, stream>>>(deg, offsets, bsums, N_NODES);
        scan2_k<<<1, 1024, 0, stream>>>(bsums, 782);
        scan3_k<<<782, 256, 0, stream>>>(offsets, bsums, cursor, N_NODES, NE);
        dinv_k<<<782, 256, 0, stream>>>(deg, dinv, N_NODES, M_PAD);
        fill_k<<<NE / 256, 256, 0, stream>>>(ei, ei + NE, cursor, csr, NE);
        gstart_k<<<33, 256, 0, stream>>>(bat, gstart, N_NODES, NG);
        f2b_pad_k<<<(M_PAD * 128) / 256, 256, 0, stream>>>(x, bufA, N_NODES * 128, M_PAD * 128);

        // layer 1: K=128 N=256
        gemm_k<0, 0><<<dim3(M_PAD / 128, 2), 256, 0, stream>>>(bufA, wc1t, bufB, 128, 256,
                                                               nullptr, nullptr, dinv, nullptr);
        agg_k<256><<<N_NODES / 4, 256, 0, stream>>>(bufB, bufA, dinv, offsets, csr, N_NODES);
        // layer 2: K=256 N=256, A = relu(agg + bc1)
        gemm_k<1, 0><<<dim3(M_PAD / 128, 2), 256, 0, stream>>>(bufA, wc2t, bufB, 256, 256,
                                                               bc1, nullptr, dinv, nullptr);
        agg_k<256><<<N_NODES / 4, 256, 0, stream>>>(bufB, bufA, dinv, offsets, csr, N_NODES);
        // layer 3
        gemm_k<1, 0><<<dim3(M_PAD / 128, 2), 256, 0, stream>>>(bufA, wc3t, bufB, 256, 256,
                                                               bc2, nullptr, dinv, nullptr);
        agg_k<256><<<N_NODES / 4, 256, 0, stream>>>(bufB, bufA, dinv, offsets, csr, N_NODES);
        // layer 4: K=256 N=128
        gemm_k<1, 0><<<dim3(M_PAD / 128, 1), 256, 0, stream>>>(bufA, wc4t, bufB, 256, 128,
                                                               bc3, nullptr, dinv, nullptr);
        agg_k<128><<<N_NODES / 4, 256, 0, stream>>>(bufB, bufA, dinv, offsets, csr, N_NODES);

        // segmented mean pool of relu(agg4 + bc4): one wave per graph
        pool2_k<<<NG / 4, 256, 0, stream>>>(bufA, bc4, gstart, cbuf + t * 128);
    }

    // notes MLPs -> cbuf cols 256..511
    for (int t = 0; t < 2; ++t) {
        const float* nt = t ? nt2 : nt1;
        f2b_pad_k<<<(NG * 128) / 256, 256, 0, stream>>>(nt, notesA, NG * 128, NG * 128);
        gemm_k<0, 1><<<dim3(NG / 128, 2), 256, 0, stream>>>(notesA, wn1t, nh, 128, 256,
                                                            nullptr, nullptr, nullptr, bn1);
        gemm_k<0, 1><<<dim3(NG / 128, 1), 256, 0, stream>>>(nh, wn2t, cbuf + 256 + t * 128, 256, 512,
                                                            nullptr, nullptr, nullptr, bn2);
    }

    // fusion head
    gemm_k<0, 1><<<dim3(NG / 128, 2), 256, 0, stream>>>(cbuf, wf1t, h1, 512, 256,
                                                        nullptr, nullptr, nullptr, bf1);
    hipMemsetAsync(colsum, 0, 2048, stream);  // colsum + colsumsq contiguous
    colred_k<<<256, 256, 0, stream>>>(h1, colsum, colsumsq, 256, 32);
    bnfin_k<<<1, 256, 0, stream>>>(colsum, colsumsq, g1, be1, scale, shift, 256);
    gemm_k<2, 1><<<dim3(NG / 128, 1), 256, 0, stream>>>(h1, wf2t, h2, 256, 128,
                                                        scale, shift, nullptr, bf2);
    hipMemsetAsync(colsum, 0, 2048, stream);
    colred_k<<<128, 128, 0, stream>>>(h2, colsum, colsumsq, 128, 64);
    bnfin_k<<<1, 128, 0, stream>>>(colsum, colsumsq, g2, be2, scale, shift, 128);
    gemm_k<2, 2><<<dim3(NG / 128, 1), 256, 0, stream>>>(h2, wf3t, d_out, 128, 128,
                                                        scale, shift, nullptr, bf3);
}

// Round 3
// 3174.641 us; speedup vs baseline: 1.4446x; 1.1928x over previous
//
#include <hip/hip_runtime.h>

typedef unsigned short u16;
typedef unsigned int u32;

#define N_NODES 200000
#define M_PAD   200064   // 128 * 1563
#define NE      3200000
#define NG      8192
#define TILE    128
#define BK      32
#define LDSTR   40       // 32 + 8 pad, keeps 16B alignment

typedef short s16x8 __attribute__((ext_vector_type(8)));
typedef float f32x4 __attribute__((ext_vector_type(4)));

__device__ __forceinline__ float bf2f(u16 u) {
    union { float f; u32 i; } x; x.i = ((u32)u) << 16; return x.f;
}
__device__ __forceinline__ u16 f2bf(float f) {
    union { float f; u32 i; } x; x.f = f;
    u32 r = (x.i + 0x7fffu + ((x.i >> 16) & 1u)) >> 16;
    return (u16)r;
}

// ---------------- degree / CSR build ----------------
__global__ void count_k(const int* __restrict__ col, int* __restrict__ deg, int e) {
    int i = blockIdx.x * 256 + threadIdx.x;
    if (i < e) atomicAdd(&deg[col[i]], 1);
}

__global__ void scan1_k(const int* __restrict__ deg, int* __restrict__ local,
                        int* __restrict__ bsums, int n) {
    __shared__ int s[256];
    int i = blockIdx.x * 256 + threadIdx.x;
    int v = (i < n) ? deg[i] : 0;
    s[threadIdx.x] = v;
    __syncthreads();
    for (int off = 1; off < 256; off <<= 1) {
        int t = (threadIdx.x >= off) ? s[threadIdx.x - off] : 0;
        __syncthreads();
        s[threadIdx.x] += t;
        __syncthreads();
    }
    if (i < n) local[i] = s[threadIdx.x] - v;  // exclusive
    if (threadIdx.x == 255) bsums[blockIdx.x] = s[255];
}

__global__ void scan2_k(int* __restrict__ bsums, int nb) {
    __shared__ int s[1024];
    int v = (threadIdx.x < nb) ? bsums[threadIdx.x] : 0;
    s[threadIdx.x] = v;
    __syncthreads();
    for (int off = 1; off < 1024; off <<= 1) {
        int t = (threadIdx.x >= off) ? s[threadIdx.x - off] : 0;
        __syncthreads();
        s[threadIdx.x] += t;
        __syncthreads();
    }
    if (threadIdx.x < nb) bsums[threadIdx.x] = s[threadIdx.x] - v;  // exclusive
}

__global__ void scan3_k(int* __restrict__ offsets, const int* __restrict__ bsums,
                        int* __restrict__ cursor, int n, int total) {
    int i = blockIdx.x * 256 + threadIdx.x;
    if (i < n) {
        int o = offsets[i] + bsums[i >> 8];
        offsets[i] = o;
        cursor[i] = o;
    }
    if (i == 0) offsets[n] = total;
}

__global__ void dinv_k(const int* __restrict__ deg, float* __restrict__ dinv,
                       int n, int npad) {
    int i = blockIdx.x * 256 + threadIdx.x;
    if (i < npad) dinv[i] = (i < n) ? rsqrtf((float)(deg[i] + 1)) : 0.f;
}

__global__ void fill_k(const int* __restrict__ row, const int* __restrict__ col,
                       int* __restrict__ cursor, int* __restrict__ csr, int e) {
    int i = blockIdx.x * 256 + threadIdx.x;
    if (i < e) {
        int p = atomicAdd(&cursor[col[i]], 1);
        csr[p] = row[i];
    }
}

// ---------------- graph segment starts (batch is sorted) ----------------
__global__ void gstart_k(const int* __restrict__ batch, int* __restrict__ gstart,
                         int n, int g) {
    int i = blockIdx.x * 256 + threadIdx.x;
    if (i > g) return;
    if (i == g) { gstart[g] = n; return; }
    int lo = 0, hi = n;
    while (lo < hi) {
        int mid = (lo + hi) >> 1;
        if (batch[mid] < i) lo = mid + 1; else hi = mid;
    }
    gstart[i] = lo;
}

// ---------------- fp32 -> bf16 (with zero-pad) ----------------
__global__ void f2b_pad_k(const float* __restrict__ x, u16* __restrict__ out,
                          int n, int ntot) {
    int i = blockIdx.x * 256 + threadIdx.x;
    if (i < ntot) out[i] = (i < n) ? f2bf(x[i]) : (u16)0;
}

// fp32 -> bf16 with per-row dinv scale (row = i >> 7 for 128-dim), zero-pad
__global__ void f2bs_k(const float* __restrict__ x, const float* __restrict__ dinv,
                       u16* __restrict__ out, int n, int ntot) {
    int i = blockIdx.x * 256 + threadIdx.x;
    if (i < ntot) out[i] = (i < n) ? f2bf(x[i] * dinv[i >> 7]) : (u16)0;
}

// ---------------- weight transpose (fp32 [K,N] -> bf16 [N,K]) ----------------
struct WtArgs {
    const float* src[9];
    u16* dst[9];
    int K[9];
    int N[9];
};
__global__ void wt_k(WtArgs a) {
    int wi = blockIdx.y;
    int K = a.K[wi], N = a.N[wi];
    int idx = blockIdx.x * 256 + threadIdx.x;
    if (idx < K * N) {
        int k = idx / N, n = idx % N;
        a.dst[wi][n * K + k] = f2bf(a.src[wi][idx]);
    }
}

// ---------------- GEMM: C[M,N] = transform(A)[M,K] @ Wt[N,K]^T ----------------
// IN_MODE: 0 = raw bf16; 1 = relu(x + p0[kcol]); 2 = x*p0[kcol] + p1[kcol]
// OUT_MODE: 0 = bf16 acc*rowscale[row]; 1 = bf16 relu(acc + outb[col]);
//           2 = f32 acc + outb[col];   3 = bf16 relu(acc + outb[col])*rowscale[row];
//           4 = bf16 acc
template<int IN_MODE, int OUT_MODE>
__global__ void __launch_bounds__(256) gemm_k(
    const u16* __restrict__ A, const u16* __restrict__ Bt, void* __restrict__ Cv,
    int K, int ldc,
    const float* __restrict__ p0, const float* __restrict__ p1,
    const float* __restrict__ rowscale, const float* __restrict__ outb)
{
    __shared__ u16 As[TILE * LDSTR];
    __shared__ u16 Bs[TILE * LDSTR];
    const int tid = threadIdx.x;
    const int lane = tid & 63;
    const int wid = tid >> 6;
    const int wm = wid & 1, wn = wid >> 1;
    const int bm0 = blockIdx.x * TILE;
    const int bn0 = blockIdx.y * TILE;

    f32x4 acc[4][4] = {};

    for (int kt = 0; kt < K; kt += BK) {
        #pragma unroll
        for (int it = 0; it < 2; ++it) {
            int idx = it * 256 + tid;
            int row = idx >> 2, cg = (idx & 3) << 3;
            const u16* srcA = A + (long)(bm0 + row) * K + kt + cg;
            uint4 va = *(const uint4*)srcA;
            if (IN_MODE != 0) {
                u16* h = (u16*)&va;
                #pragma unroll
                for (int j = 0; j < 8; ++j) {
                    float f = bf2f(h[j]);
                    int c = kt + cg + j;
                    if (IN_MODE == 1) f = fmaxf(f + p0[c], 0.f);
                    else               f = f * p0[c] + p1[c];
                    h[j] = f2bf(f);
                }
            }
            *(uint4*)&As[row * LDSTR + cg] = va;
            const u16* srcB = Bt + (long)(bn0 + row) * K + kt + cg;
            *(uint4*)&Bs[row * LDSTR + cg] = *(const uint4*)srcB;
        }
        __syncthreads();

        s16x8 af[4], bfr[4];
        int koff = (lane >> 4) << 3;
        #pragma unroll
        for (int i = 0; i < 4; ++i) {
            int rA = wm * 64 + i * 16 + (lane & 15);
            af[i] = *(const s16x8*)&As[rA * LDSTR + koff];
            int rB = wn * 64 + i * 16 + (lane & 15);
            bfr[i] = *(const s16x8*)&Bs[rB * LDSTR + koff];
        }
        #pragma unroll
        for (int i = 0; i < 4; ++i)
            #pragma unroll
            for (int j = 0; j < 4; ++j)
                acc[i][j] = __builtin_amdgcn_mfma_f32_16x16x32_bf16(af[i], bfr[j], acc[i][j], 0, 0, 0);
        __syncthreads();
    }

    #pragma unroll
    for (int i = 0; i < 4; ++i) {
        int rbase = wm * 64 + i * 16 + ((lane >> 4) << 2);
        #pragma unroll
        for (int j = 0; j < 4; ++j) {
            int col = bn0 + wn * 64 + j * 16 + (lane & 15);
            #pragma unroll
            for (int r = 0; r < 4; ++r) {
                long row = bm0 + rbase + r;
                float v = acc[i][j][r];
                if (OUT_MODE == 0) {
                    v *= rowscale[row];
                    ((u16*)Cv)[row * ldc + col] = f2bf(v);
                } else if (OUT_MODE == 1) {
                    v = fmaxf(v + outb[col], 0.f);
                    ((u16*)Cv)[row * ldc + col] = f2bf(v);
                } else if (OUT_MODE == 2) {
                    ((float*)Cv)[row * ldc + col] = v + outb[col];
                } else if (OUT_MODE == 3) {
                    v = fmaxf(v + outb[col], 0.f) * rowscale[row];
                    ((u16*)Cv)[row * ldc + col] = f2bf(v);
                } else {
                    ((u16*)Cv)[row * ldc + col] = f2bf(v);
                }
            }
        }
    }
}

// ---------------- aggregation: out[c] = dinv[c] * (hs[c] + sum_{nbr} hs[nbr]) ----------------
template<int DIM>
__global__ void __launch_bounds__(256) agg_k(
    const u16* __restrict__ hs, u16* __restrict__ out,
    const float* __restrict__ dinv, const int* __restrict__ offs,
    const int* __restrict__ rows, int n)
{
    constexpr int VPL = DIM / 64;  // 4 (DIM=256, uint2) or 2 (DIM=128, u32)
    int node = (blockIdx.x << 2) + (threadIdx.x >> 6);
    if (node >= n) return;
    int lane = threadIdx.x & 63;

    float acc[VPL];
    uint2 u0, u1, u2, u3;
    u32 w0, w1, w2, w3;

    auto ld = [&](int r, uint2& u, u32& w) {
        const u16* q = hs + (size_t)r * DIM + lane * VPL;
        if constexpr (VPL == 4) u = *(const uint2*)q;
        else                    w = *(const u32*)q;
    };
    auto add = [&](const uint2& u, const u32& w) {
        if constexpr (VPL == 4) {
            acc[0] += bf2f((u16)u.x); acc[1] += bf2f((u16)(u.x >> 16));
            acc[2] += bf2f((u16)u.y); acc[3] += bf2f((u16)(u.y >> 16));
        } else {
            acc[0] += bf2f((u16)w);   acc[1] += bf2f((u16)(w >> 16));
        }
    };

    {
        #pragma unroll
        for (int v = 0; v < VPL; ++v) acc[v] = 0.f;
        ld(node, u0, w0);
        add(u0, w0);
    }

    int b = offs[node], e = offs[node + 1];
    int j = b;
    for (; j + 3 < e; j += 4) {
        int r0 = rows[j], r1 = rows[j + 1], r2 = rows[j + 2], r3 = rows[j + 3];
        ld(r0, u0, w0); ld(r1, u1, w1); ld(r2, u2, w2); ld(r3, u3, w3);
        add(u0, w0); add(u1, w1); add(u2, w2); add(u3, w3);
    }
    for (; j < e; ++j) {
        int r0 = rows[j];
        ld(r0, u0, w0);
        add(u0, w0);
    }

    float dv = dinv[node];
    u16 o[VPL];
    #pragma unroll
    for (int v = 0; v < VPL; ++v) o[v] = f2bf(acc[v] * dv);
    u16* op = out + (size_t)node * DIM + lane * VPL;
    if constexpr (VPL == 4) *(uint2*)op = *(uint2*)o;
    else                    *(u32*)op  = *(u32*)o;
}

// ---------------- segmented mean pool: one wave per graph (batch sorted) ----------------
__global__ void __launch_bounds__(256) pool2_k(
    const u16* __restrict__ agg, const float* __restrict__ b4,
    const int* __restrict__ gstart, u16* __restrict__ dst)
{
    int g = (blockIdx.x << 2) + (threadIdx.x >> 6);
    int lane = threadIdx.x & 63;
    int s = gstart[g], e = gstart[g + 1];
    float bias0 = b4[lane * 2], bias1 = b4[lane * 2 + 1];
    float a0 = 0.f, a1 = 0.f;
    for (int n = s; n < e; ++n) {
        u32 u = *(const u32*)(agg + (size_t)n * 128 + lane * 2);
        a0 += fmaxf(bf2f((u16)u) + bias0, 0.f);
        a1 += fmaxf(bf2f((u16)(u >> 16)) + bias1, 0.f);
    }
    float c = 1.f / fmaxf((float)(e - s), 1.f);
    dst[(size_t)g * 512 + lane * 2]     = f2bf(a0 * c);
    dst[(size_t)g * 512 + lane * 2 + 1] = f2bf(a1 * c);
}

// ---------------- batch-norm stats ----------------
__global__ void colred_k(const u16* __restrict__ h, float* __restrict__ sum,
                         float* __restrict__ sumsq, int N, int rowsPer) {
    int col = threadIdx.x;
    long r0 = (long)blockIdx.x * rowsPer;
    float s = 0.f, s2 = 0.f;
    for (int r = 0; r < rowsPer; ++r) {
        float v = bf2f(h[(r0 + r) * N + col]);
        s += v; s2 += v * v;
    }
    atomicAdd(&sum[col], s);
    atomicAdd(&sumsq[col], s2);
}

__global__ void bnfin_k(const float* __restrict__ sum, const float* __restrict__ sumsq,
                        const float* __restrict__ g, const float* __restrict__ be,
                        float* __restrict__ scale, float* __restrict__ shift, int N) {
    int i = threadIdx.x;
    if (i >= N) return;
    float mu = sum[i] * (1.f / 8192.f);
    float var = sumsq[i] * (1.f / 8192.f) - mu * mu;
    float sc = g[i] * rsqrtf(var + 1e-5f);
    scale[i] = sc;
    shift[i] = be[i] - mu * sc;
}

// ---------------- host ----------------
extern "C" void kernel_launch(void* const* d_in, const int* in_sizes, int n_in,
                              void* d_out, int out_size, void* d_ws, size_t ws_size,
                              hipStream_t stream) {
    const float* x1 = (const float*)d_in[0];
    const float* x2 = (const float*)d_in[1];
    const int* ei1 = (const int*)d_in[2];
    const int* ei2 = (const int*)d_in[3];
    const int* bt1 = (const int*)d_in[4];
    const int* bt2 = (const int*)d_in[5];
    const float* nt1 = (const float*)d_in[6];
    const float* nt2 = (const float*)d_in[7];
    const float* Wc1 = (const float*)d_in[8];  const float* bc1 = (const float*)d_in[9];
    const float* Wc2 = (const float*)d_in[10]; const float* bc2 = (const float*)d_in[11];
    const float* Wc3 = (const float*)d_in[12]; const float* bc3 = (const float*)d_in[13];
    const float* Wc4 = (const float*)d_in[14]; const float* bc4 = (const float*)d_in[15];
    const float* Wn1 = (const float*)d_in[16]; const float* bn1 = (const float*)d_in[17];
    const float* Wn2 = (const float*)d_in[18]; const float* bn2 = (const float*)d_in[19];
    const float* Wf1 = (const float*)d_in[20]; const float* bf1 = (const float*)d_in[21];
    const float* g1  = (const float*)d_in[22]; const float* be1 = (const float*)d_in[23];
    const float* Wf2 = (const float*)d_in[24]; const float* bf2 = (const float*)d_in[25];
    const float* g2  = (const float*)d_in[26]; const float* be2 = (const float*)d_in[27];
    const float* Wf3 = (const float*)d_in[28]; const float* bf3 = (const float*)d_in[29];

    char* base = (char*)d_ws;
    size_t off = 0;
    auto alloc = [&](size_t bytes) -> char* {
        char* r = base + off;
        off = (off + bytes + 255) & ~(size_t)255;
        return r;
    };
    u16*   bufA    = (u16*)  alloc((size_t)M_PAD * 256 * 2);
    u16*   bufB    = (u16*)  alloc((size_t)M_PAD * 256 * 2);
    int*   csr     = (int*)  alloc((size_t)NE * 4);
    int*   offsets = (int*)  alloc((size_t)(N_NODES + 1) * 4);
    int*   cursor  = (int*)  alloc((size_t)N_NODES * 4);
    int*   deg     = (int*)  alloc((size_t)N_NODES * 4);
    float* dinv    = (float*)alloc((size_t)M_PAD * 4);
    int*   bsums   = (int*)  alloc(4096);
    int*   gstart  = (int*)  alloc((size_t)(NG + 1) * 4);
    u16*   wt      = (u16*)  alloc(442368 * 2);
    u16*   cbuf    = (u16*)  alloc((size_t)NG * 512 * 2);
    u16*   nh      = (u16*)  alloc((size_t)NG * 256 * 2);
    u16*   notesA  = (u16*)  alloc((size_t)NG * 128 * 2);
    u16*   h1      = (u16*)  alloc((size_t)NG * 256 * 2);
    u16*   h2      = (u16*)  alloc((size_t)NG * 128 * 2);
    float* colsum  = (float*)alloc(1024);
    float* colsumsq= (float*)alloc(1024);
    float* scale   = (float*)alloc(1024);
    float* shift   = (float*)alloc(1024);
    if (off > ws_size) return;

    u16* wc1t = wt;            u16* wc2t = wt + 32768;  u16* wc3t = wt + 98304;
    u16* wc4t = wt + 163840;   u16* wn1t = wt + 196608; u16* wn2t = wt + 229376;
    u16* wf1t = wt + 262144;   u16* wf2t = wt + 393216; u16* wf3t = wt + 425984;
    {
        WtArgs wa;
        const float* s[9] = {Wc1, Wc2, Wc3, Wc4, Wn1, Wn2, Wf1, Wf2, Wf3};
        u16* dsts[9]      = {wc1t, wc2t, wc3t, wc4t, wn1t, wn2t, wf1t, wf2t, wf3t};
        int Ks[9] = {128, 256, 256, 256, 128, 256, 512, 256, 128};
        int Ns[9] = {256, 256, 256, 128, 256, 128, 256, 128, 128};
        for (int i = 0; i < 9; ++i) { wa.src[i] = s[i]; wa.dst[i] = dsts[i]; wa.K[i] = Ks[i]; wa.N[i] = Ns[i]; }
        hipLaunchKernelGGL(wt_k, dim3(512, 9), dim3(256), 0, stream, wa);
    }

    for (int t = 0; t < 2; ++t) {
        const float* x   = t ? x2 : x1;
        const int*   ei  = t ? ei2 : ei1;
        const int*   bat = t ? bt2 : bt1;

        hipMemsetAsync(deg, 0, (size_t)N_NODES * 4, stream);
        count_k<<<NE / 256, 256, 0, stream>>>(ei + NE, deg, NE);
        scan1_k<<<782, 256, 0, stream>>>(deg, offsets, bsums, N_NODES);
        scan2_k<<<1, 1024, 0, stream>>>(bsums, 782);
        scan3_k<<<782, 256, 0, stream>>>(offsets, bsums, cursor, N_NODES, NE);
        dinv_k<<<782, 256, 0, stream>>>(deg, dinv, N_NODES, M_PAD);
        fill_k<<<NE / 256, 256, 0, stream>>>(ei, ei + NE, cursor, csr, NE);
        gstart_k<<<33, 256, 0, stream>>>(bat, gstart, N_NODES, NG);
        // xs = bf16(x * dinv[row])  [M_PAD x 128]
        f2bs_k<<<(M_PAD * 128) / 256, 256, 0, stream>>>(x, dinv, bufA, N_NODES * 128, M_PAD * 128);

        // layer 1 (agg commuted before GEMM, 128-dim gather):
        agg_k<128><<<N_NODES / 4 + 1, 256, 0, stream>>>(bufA, bufB, dinv, offsets, csr, N_NODES);
        // h1s = relu(xa @ W1 + bc1) * dinv   [OUT_MODE 3]
        gemm_k<0, 3><<<dim3(M_PAD / 128, 2), 256, 0, stream>>>(bufB, wc1t, bufA, 128, 256,
                                                               nullptr, nullptr, dinv, bc1);
        // layer 2: hs2 = h1s @ W2 (plain bf16 out)
        gemm_k<0, 4><<<dim3(M_PAD / 128, 2), 256, 0, stream>>>(bufA, wc2t, bufB, 256, 256,
                                                               nullptr, nullptr, nullptr, nullptr);
        agg_k<256><<<N_NODES / 4 + 1, 256, 0, stream>>>(bufB, bufA, dinv, offsets, csr, N_NODES);
        // layer 3: hs3 = (relu(a2 + bc2) @ W3) * dinv
        gemm_k<1, 0><<<dim3(M_PAD / 128, 2), 256, 0, stream>>>(bufA, wc3t, bufB, 256, 256,
                                                               bc2, nullptr, dinv, nullptr);
        agg_k<256><<<N_NODES / 4 + 1, 256, 0, stream>>>(bufB, bufA, dinv, offsets, csr, N_NODES);
        // layer 4: hs4 = (relu(a3 + bc3) @ W4) * dinv   K=256 N=128
        gemm_k<1, 0><<<dim3(M_PAD / 128, 1), 256, 0, stream>>>(bufA, wc4t, bufB, 256, 128,
                                                               bc3, nullptr, dinv, nullptr);
        agg_k<128><<<N_NODES / 4 + 1, 256, 0, stream>>>(bufB, bufA, dinv, offsets, csr, N_NODES);

        pool2_k<<<NG / 4, 256, 0, stream>>>(bufA, bc4, gstart, cbuf + t * 128);
    }

    // notes MLPs -> cbuf cols 256..511
    for (int t = 0; t < 2; ++t) {
        const float* nt = t ? nt2 : nt1;
        f2b_pad_k<<<(NG * 128) / 256, 256, 0, stream>>>(nt, notesA, NG * 128, NG * 128);
        gemm_k<0, 1><<<dim3(NG / 128, 2), 256, 0, stream>>>(notesA, wn1t, nh, 128, 256,
                                                            nullptr, nullptr, nullptr, bn1);
        gemm_k<0, 1><<<dim3(NG / 128, 1), 256, 0, stream>>>(nh, wn2t, cbuf + 256 + t * 128, 256, 512,
                                                            nullptr, nullptr, nullptr, bn2);
    }

    // fusion head
    gemm_k<0, 1><<<dim3(NG / 128, 2), 256, 0, stream>>>(cbuf, wf1t, h1, 512, 256,
                                                        nullptr, nullptr, nullptr, bf1);
    hipMemsetAsync(colsum, 0, 2048, stream);
    colred_k<<<256, 256, 0, stream>>>(h1, colsum, colsumsq, 256, 32);
    bnfin_k<<<1, 256, 0, stream>>>(colsum, colsumsq, g1, be1, scale, shift, 256);
    gemm_k<2, 1><<<dim3(NG / 128, 1), 256, 0, stream>>>(h1, wf2t, h2, 256, 128,
                                                        scale, shift, nullptr, bf2);
    hipMemsetAsync(colsum, 0, 2048, stream);
    colred_k<<<128, 128, 0, stream>>>(h2, colsum, colsumsq, 128, 64);
    bnfin_k<<<1, 128, 0, stream>>>(colsum, colsumsq, g2, be2, scale, shift, 128);
    gemm_k<2, 2><<<dim3(NG / 128, 1), 256, 0, stream>>>(h2, wf3t, d_out, 128, 128,
                                                        scale, shift, nullptr, bf3);
}

// Round 4
// 2946.645 us; speedup vs baseline: 1.5564x; 1.0774x over previous
//
#include <hip/hip_runtime.h>

typedef unsigned short u16;
typedef unsigned int u32;

#define N_NODES 200000
#define M_PAD   200064   // 128 * 1563
#define NE      3200000
#define NG      8192
#define TILE    128
#define BK      32
#define LDSTR   40       // 32 + 8 pad, keeps 16B alignment
#define NPASS   8
#define SLICE   (N_NODES / NPASS)   // 25000

typedef short s16x8 __attribute__((ext_vector_type(8)));
typedef float f32x4 __attribute__((ext_vector_type(4)));

__device__ __forceinline__ float bf2f(u16 u) {
    union { float f; u32 i; } x; x.i = ((u32)u) << 16; return x.f;
}
__device__ __forceinline__ u16 f2bf(float f) {
    union { float f; u32 i; } x; x.f = f;
    u32 r = (x.i + 0x7fffu + ((x.i >> 16) & 1u)) >> 16;
    return (u16)r;
}

// ---------------- degree / CSR build ----------------
__global__ void count_k(const int* __restrict__ col, int* __restrict__ deg, int e) {
    int i = blockIdx.x * 256 + threadIdx.x;
    if (i < e) atomicAdd(&deg[col[i]], 1);
}

__global__ void scan1_k(const int* __restrict__ deg, int* __restrict__ local,
                        int* __restrict__ bsums, int n) {
    __shared__ int s[256];
    int i = blockIdx.x * 256 + threadIdx.x;
    int v = (i < n) ? deg[i] : 0;
    s[threadIdx.x] = v;
    __syncthreads();
    for (int off = 1; off < 256; off <<= 1) {
        int t = (threadIdx.x >= off) ? s[threadIdx.x - off] : 0;
        __syncthreads();
        s[threadIdx.x] += t;
        __syncthreads();
    }
    if (i < n) local[i] = s[threadIdx.x] - v;  // exclusive
    if (threadIdx.x == 255) bsums[blockIdx.x] = s[255];
}

__global__ void scan2_k(int* __restrict__ bsums, int nb) {
    __shared__ int s[1024];
    int v = (threadIdx.x < nb) ? bsums[threadIdx.x] : 0;
    s[threadIdx.x] = v;
    __syncthreads();
    for (int off = 1; off < 1024; off <<= 1) {
        int t = (threadIdx.x >= off) ? s[threadIdx.x - off] : 0;
        __syncthreads();
        s[threadIdx.x] += t;
        __syncthreads();
    }
    if (threadIdx.x < nb) bsums[threadIdx.x] = s[threadIdx.x] - v;  // exclusive
}

__global__ void scan3_k(int* __restrict__ offsets, const int* __restrict__ bsums,
                        int* __restrict__ cursor, int n, int total) {
    int i = blockIdx.x * 256 + threadIdx.x;
    if (i < n) {
        int o = offsets[i] + bsums[i >> 8];
        offsets[i] = o;
        cursor[i] = o;
    }
    if (i == 0) offsets[n] = total;
}

__global__ void dinv_k(const int* __restrict__ deg, float* __restrict__ dinv,
                       int n, int npad) {
    int i = blockIdx.x * 256 + threadIdx.x;
    if (i < npad) dinv[i] = (i < n) ? rsqrtf((float)(deg[i] + 1)) : 0.f;
}

// multipass dest-sliced fill: sweep p only scatters into csr slice p (L2-resident)
__global__ void fill2_k(const int* __restrict__ row, const int* __restrict__ col,
                        int* __restrict__ cursor, int* __restrict__ csr, int e) {
    int tid = blockIdx.x * 256 + threadIdx.x;
    int stride = gridDim.x * 256;
    for (int p = 0; p < NPASS; ++p) {
        int lo = p * SLICE, hi = lo + SLICE;
        for (int i = tid; i < e; i += stride) {
            int c = col[i];
            if (c >= lo && c < hi) {
                int pos = atomicAdd(&cursor[c], 1);
                csr[pos] = row[i];
            }
        }
    }
}

// ---------------- graph segment starts (batch is sorted) ----------------
__global__ void gstart_k(const int* __restrict__ batch, int* __restrict__ gstart,
                         int n, int g) {
    int i = blockIdx.x * 256 + threadIdx.x;
    if (i > g) return;
    if (i == g) { gstart[g] = n; return; }
    int lo = 0, hi = n;
    while (lo < hi) {
        int mid = (lo + hi) >> 1;
        if (batch[mid] < i) lo = mid + 1; else hi = mid;
    }
    gstart[i] = lo;
}

// ---------------- fp32 -> bf16 (with zero-pad) ----------------
__global__ void f2b_pad_k(const float* __restrict__ x, u16* __restrict__ out,
                          int n, int ntot) {
    int i = blockIdx.x * 256 + threadIdx.x;
    if (i < ntot) out[i] = (i < n) ? f2bf(x[i]) : (u16)0;
}

// fp32 -> bf16 with per-row dinv scale (row = i >> 7 for 128-dim), zero-pad
__global__ void f2bs_k(const float* __restrict__ x, const float* __restrict__ dinv,
                       u16* __restrict__ out, int n, int ntot) {
    int i = blockIdx.x * 256 + threadIdx.x;
    if (i < ntot) out[i] = (i < n) ? f2bf(x[i] * dinv[i >> 7]) : (u16)0;
}

// ---------------- weight transpose (fp32 [K,N] -> bf16 [N,K]) ----------------
struct WtArgs {
    const float* src[9];
    u16* dst[9];
    int K[9];
    int N[9];
};
__global__ void wt_k(WtArgs a) {
    int wi = blockIdx.y;
    int K = a.K[wi], N = a.N[wi];
    int idx = blockIdx.x * 256 + threadIdx.x;
    if (idx < K * N) {
        int k = idx / N, n = idx % N;
        a.dst[wi][n * K + k] = f2bf(a.src[wi][idx]);
    }
}

// ---------------- GEMM: C[M,N] = transform(A)[M,K] @ Wt[N,K]^T ----------------
// IN_MODE: 0 = raw bf16; 1 = relu(x + p0[kcol]); 2 = x*p0[kcol] + p1[kcol]
// OUT_MODE: 0 = bf16 acc*rowscale[row]; 1 = bf16 relu(acc + outb[col]);
//           2 = f32 acc + outb[col];   3 = bf16 relu(acc + outb[col])*rowscale[row];
//           4 = bf16 acc
template<int IN_MODE, int OUT_MODE>
__global__ void __launch_bounds__(256) gemm_k(
    const u16* __restrict__ A, const u16* __restrict__ Bt, void* __restrict__ Cv,
    int K, int ldc,
    const float* __restrict__ p0, const float* __restrict__ p1,
    const float* __restrict__ rowscale, const float* __restrict__ outb)
{
    __shared__ u16 As[TILE * LDSTR];
    __shared__ u16 Bs[TILE * LDSTR];
    const int tid = threadIdx.x;
    const int lane = tid & 63;
    const int wid = tid >> 6;
    const int wm = wid & 1, wn = wid >> 1;
    const int bm0 = blockIdx.x * TILE;
    const int bn0 = blockIdx.y * TILE;

    f32x4 acc[4][4] = {};

    for (int kt = 0; kt < K; kt += BK) {
        #pragma unroll
        for (int it = 0; it < 2; ++it) {
            int idx = it * 256 + tid;
            int row = idx >> 2, cg = (idx & 3) << 3;
            const u16* srcA = A + (long)(bm0 + row) * K + kt + cg;
            uint4 va = *(const uint4*)srcA;
            if (IN_MODE != 0) {
                u16* h = (u16*)&va;
                #pragma unroll
                for (int j = 0; j < 8; ++j) {
                    float f = bf2f(h[j]);
                    int c = kt + cg + j;
                    if (IN_MODE == 1) f = fmaxf(f + p0[c], 0.f);
                    else               f = f * p0[c] + p1[c];
                    h[j] = f2bf(f);
                }
            }
            *(uint4*)&As[row * LDSTR + cg] = va;
            const u16* srcB = Bt + (long)(bn0 + row) * K + kt + cg;
            *(uint4*)&Bs[row * LDSTR + cg] = *(const uint4*)srcB;
        }
        __syncthreads();

        s16x8 af[4], bfr[4];
        int koff = (lane >> 4) << 3;
        #pragma unroll
        for (int i = 0; i < 4; ++i) {
            int rA = wm * 64 + i * 16 + (lane & 15);
            af[i] = *(const s16x8*)&As[rA * LDSTR + koff];
            int rB = wn * 64 + i * 16 + (lane & 15);
            bfr[i] = *(const s16x8*)&Bs[rB * LDSTR + koff];
        }
        #pragma unroll
        for (int i = 0; i < 4; ++i)
            #pragma unroll
            for (int j = 0; j < 4; ++j)
                acc[i][j] = __builtin_amdgcn_mfma_f32_16x16x32_bf16(af[i], bfr[j], acc[i][j], 0, 0, 0);
        __syncthreads();
    }

    #pragma unroll
    for (int i = 0; i < 4; ++i) {
        int rbase = wm * 64 + i * 16 + ((lane >> 4) << 2);
        #pragma unroll
        for (int j = 0; j < 4; ++j) {
            int col = bn0 + wn * 64 + j * 16 + (lane & 15);
            #pragma unroll
            for (int r = 0; r < 4; ++r) {
                long row = bm0 + rbase + r;
                float v = acc[i][j][r];
                if (OUT_MODE == 0) {
                    v *= rowscale[row];
                    ((u16*)Cv)[row * ldc + col] = f2bf(v);
                } else if (OUT_MODE == 1) {
                    v = fmaxf(v + outb[col], 0.f);
                    ((u16*)Cv)[row * ldc + col] = f2bf(v);
                } else if (OUT_MODE == 2) {
                    ((float*)Cv)[row * ldc + col] = v + outb[col];
                } else if (OUT_MODE == 3) {
                    v = fmaxf(v + outb[col], 0.f) * rowscale[row];
                    ((u16*)Cv)[row * ldc + col] = f2bf(v);
                } else {
                    ((u16*)Cv)[row * ldc + col] = f2bf(v);
                }
            }
        }
    }
}

// ---------------- aggregation: out[c] = dinv[c] * (hs[c] + sum_{nbr} hs[nbr]) ----------------
template<int DIM>
__global__ void __launch_bounds__(256) agg_k(
    const u16* __restrict__ hs, u16* __restrict__ out,
    const float* __restrict__ dinv, const int* __restrict__ offs,
    const int* __restrict__ rows, int n)
{
    constexpr int VPL = DIM / 64;  // 4 (DIM=256, uint2) or 2 (DIM=128, u32)
    int node = (blockIdx.x << 2) + (threadIdx.x >> 6);
    if (node >= n) return;
    int lane = threadIdx.x & 63;

    float acc[VPL];
    uint2 u[8];
    u32 w[8];

    auto ld = [&](int r, int s) {
        const u16* q = hs + (size_t)r * DIM + lane * VPL;
        if constexpr (VPL == 4) u[s] = *(const uint2*)q;
        else                    w[s] = *(const u32*)q;
    };
    auto add = [&](int s) {
        if constexpr (VPL == 4) {
            acc[0] += bf2f((u16)u[s].x); acc[1] += bf2f((u16)(u[s].x >> 16));
            acc[2] += bf2f((u16)u[s].y); acc[3] += bf2f((u16)(u[s].y >> 16));
        } else {
            acc[0] += bf2f((u16)w[s]);   acc[1] += bf2f((u16)(w[s] >> 16));
        }
    };

    {
        #pragma unroll
        for (int v = 0; v < VPL; ++v) acc[v] = 0.f;
        ld(node, 0);
        add(0);
    }

    int b = offs[node], e = offs[node + 1];
    int j = b;
    for (; j + 7 < e; j += 8) {
        int r[8];
        #pragma unroll
        for (int s = 0; s < 8; ++s) r[s] = rows[j + s];
        #pragma unroll
        for (int s = 0; s < 8; ++s) ld(r[s], s);
        #pragma unroll
        for (int s = 0; s < 8; ++s) add(s);
    }
    for (; j + 3 < e; j += 4) {
        int r[4];
        #pragma unroll
        for (int s = 0; s < 4; ++s) r[s] = rows[j + s];
        #pragma unroll
        for (int s = 0; s < 4; ++s) ld(r[s], s);
        #pragma unroll
        for (int s = 0; s < 4; ++s) add(s);
    }
    for (; j < e; ++j) {
        ld(rows[j], 0);
        add(0);
    }

    float dv = dinv[node];
    u16 o[VPL];
    #pragma unroll
    for (int v = 0; v < VPL; ++v) o[v] = f2bf(acc[v] * dv);
    u16* op = out + (size_t)node * DIM + lane * VPL;
    if constexpr (VPL == 4) *(uint2*)op = *(uint2*)o;
    else                    *(u32*)op  = *(u32*)o;
}

// ---------------- segmented mean pool: one wave per graph (batch sorted) ----------------
__global__ void __launch_bounds__(256) pool2_k(
    const u16* __restrict__ agg, const float* __restrict__ b4,
    const int* __restrict__ gstart, u16* __restrict__ dst)
{
    int g = (blockIdx.x << 2) + (threadIdx.x >> 6);
    int lane = threadIdx.x & 63;
    int s = gstart[g], e = gstart[g + 1];
    float bias0 = b4[lane * 2], bias1 = b4[lane * 2 + 1];
    float a0 = 0.f, a1 = 0.f;
    for (int n = s; n < e; ++n) {
        u32 u = *(const u32*)(agg + (size_t)n * 128 + lane * 2);
        a0 += fmaxf(bf2f((u16)u) + bias0, 0.f);
        a1 += fmaxf(bf2f((u16)(u >> 16)) + bias1, 0.f);
    }
    float c = 1.f / fmaxf((float)(e - s), 1.f);
    dst[(size_t)g * 512 + lane * 2]     = f2bf(a0 * c);
    dst[(size_t)g * 512 + lane * 2 + 1] = f2bf(a1 * c);
}

// ---------------- batch-norm stats ----------------
__global__ void colred_k(const u16* __restrict__ h, float* __restrict__ sum,
                         float* __restrict__ sumsq, int N, int rowsPer) {
    int col = threadIdx.x;
    long r0 = (long)blockIdx.x * rowsPer;
    float s = 0.f, s2 = 0.f;
    for (int r = 0; r < rowsPer; ++r) {
        float v = bf2f(h[(r0 + r) * N + col]);
        s += v; s2 += v * v;
    }
    atomicAdd(&sum[col], s);
    atomicAdd(&sumsq[col], s2);
}

__global__ void bnfin_k(const float* __restrict__ sum, const float* __restrict__ sumsq,
                        const float* __restrict__ g, const float* __restrict__ be,
                        float* __restrict__ scale, float* __restrict__ shift, int N) {
    int i = threadIdx.x;
    if (i >= N) return;
    float mu = sum[i] * (1.f / 8192.f);
    float var = sumsq[i] * (1.f / 8192.f) - mu * mu;
    float sc = g[i] * rsqrtf(var + 1e-5f);
    scale[i] = sc;
    shift[i] = be[i] - mu * sc;
}

// ---------------- host ----------------
extern "C" void kernel_launch(void* const* d_in, const int* in_sizes, int n_in,
                              void* d_out, int out_size, void* d_ws, size_t ws_size,
                              hipStream_t stream) {
    const float* x1 = (const float*)d_in[0];
    const float* x2 = (const float*)d_in[1];
    const int* ei1 = (const int*)d_in[2];
    const int* ei2 = (const int*)d_in[3];
    const int* bt1 = (const int*)d_in[4];
    const int* bt2 = (const int*)d_in[5];
    const float* nt1 = (const float*)d_in[6];
    const float* nt2 = (const float*)d_in[7];
    const float* Wc1 = (const float*)d_in[8];  const float* bc1 = (const float*)d_in[9];
    const float* Wc2 = (const float*)d_in[10]; const float* bc2 = (const float*)d_in[11];
    const float* Wc3 = (const float*)d_in[12]; const float* bc3 = (const float*)d_in[13];
    const float* Wc4 = (const float*)d_in[14]; const float* bc4 = (const float*)d_in[15];
    const float* Wn1 = (const float*)d_in[16]; const float* bn1 = (const float*)d_in[17];
    const float* Wn2 = (const float*)d_in[18]; const float* bn2 = (const float*)d_in[19];
    const float* Wf1 = (const float*)d_in[20]; const float* bf1 = (const float*)d_in[21];
    const float* g1  = (const float*)d_in[22]; const float* be1 = (const float*)d_in[23];
    const float* Wf2 = (const float*)d_in[24]; const float* bf2 = (const float*)d_in[25];
    const float* g2  = (const float*)d_in[26]; const float* be2 = (const float*)d_in[27];
    const float* Wf3 = (const float*)d_in[28]; const float* bf3 = (const float*)d_in[29];

    char* base = (char*)d_ws;
    size_t off = 0;
    auto alloc = [&](size_t bytes) -> char* {
        char* r = base + off;
        off = (off + bytes + 255) & ~(size_t)255;
        return r;
    };
    u16*   bufA    = (u16*)  alloc((size_t)M_PAD * 256 * 2);
    u16*   bufB    = (u16*)  alloc((size_t)M_PAD * 256 * 2);
    int*   csr     = (int*)  alloc((size_t)NE * 4);
    int*   offsets = (int*)  alloc((size_t)(N_NODES + 1) * 4);
    int*   cursor  = (int*)  alloc((size_t)N_NODES * 4);
    int*   deg     = (int*)  alloc((size_t)N_NODES * 4);
    float* dinv    = (float*)alloc((size_t)M_PAD * 4);
    int*   bsums   = (int*)  alloc(4096);
    int*   gstart  = (int*)  alloc((size_t)(NG + 1) * 4);
    u16*   wt      = (u16*)  alloc(442368 * 2);
    u16*   cbuf    = (u16*)  alloc((size_t)NG * 512 * 2);
    u16*   nh      = (u16*)  alloc((size_t)NG * 256 * 2);
    u16*   notesA  = (u16*)  alloc((size_t)NG * 128 * 2);
    u16*   h1      = (u16*)  alloc((size_t)NG * 256 * 2);
    u16*   h2      = (u16*)  alloc((size_t)NG * 128 * 2);
    float* colsum  = (float*)alloc(1024);
    float* colsumsq= (float*)alloc(1024);
    float* scale   = (float*)alloc(1024);
    float* shift   = (float*)alloc(1024);
    if (off > ws_size) return;

    u16* wc1t = wt;            u16* wc2t = wt + 32768;  u16* wc3t = wt + 98304;
    u16* wc4t = wt + 163840;   u16* wn1t = wt + 196608; u16* wn2t = wt + 229376;
    u16* wf1t = wt + 262144;   u16* wf2t = wt + 393216; u16* wf3t = wt + 425984;
    {
        WtArgs wa;
        const float* s[9] = {Wc1, Wc2, Wc3, Wc4, Wn1, Wn2, Wf1, Wf2, Wf3};
        u16* dsts[9]      = {wc1t, wc2t, wc3t, wc4t, wn1t, wn2t, wf1t, wf2t, wf3t};
        int Ks[9] = {128, 256, 256, 256, 128, 256, 512, 256, 128};
        int Ns[9] = {256, 256, 256, 128, 256, 128, 256, 128, 128};
        for (int i = 0; i < 9; ++i) { wa.src[i] = s[i]; wa.dst[i] = dsts[i]; wa.K[i] = Ks[i]; wa.N[i] = Ns[i]; }
        hipLaunchKernelGGL(wt_k, dim3(512, 9), dim3(256), 0, stream, wa);
    }

    for (int t = 0; t < 2; ++t) {
        const float* x   = t ? x2 : x1;
        const int*   ei  = t ? ei2 : ei1;
        const int*   bat = t ? bt2 : bt1;

        hipMemsetAsync(deg, 0, (size_t)N_NODES * 4, stream);
        count_k<<<NE / 256, 256, 0, stream>>>(ei + NE, deg, NE);
        scan1_k<<<782, 256, 0, stream>>>(deg, offsets, bsums, N_NODES);
        scan2_k<<<1, 1024, 0, stream>>>(bsums, 782);
        scan3_k<<<782, 256, 0, stream>>>(offsets, bsums, cursor, N_NODES, NE);
        dinv_k<<<782, 256, 0, stream>>>(deg, dinv, N_NODES, M_PAD);
        fill2_k<<<2048, 256, 0, stream>>>(ei, ei + NE, cursor, csr, NE);
        gstart_k<<<33, 256, 0, stream>>>(bat, gstart, N_NODES, NG);
        // xs = bf16(x * dinv[row])  [M_PAD x 128]
        f2bs_k<<<(M_PAD * 128) / 256, 256, 0, stream>>>(x, dinv, bufA, N_NODES * 128, M_PAD * 128);

        // layer 1 (agg commuted before GEMM, 128-dim gather):
        agg_k<128><<<N_NODES / 4 + 1, 256, 0, stream>>>(bufA, bufB, dinv, offsets, csr, N_NODES);
        // h1s = relu(xa @ W1 + bc1) * dinv   [OUT_MODE 3]
        gemm_k<0, 3><<<dim3(M_PAD / 128, 2), 256, 0, stream>>>(bufB, wc1t, bufA, 128, 256,
                                                               nullptr, nullptr, dinv, bc1);
        // layer 2: hs2 = h1s @ W2 (plain bf16 out)
        gemm_k<0, 4><<<dim3(M_PAD / 128, 2), 256, 0, stream>>>(bufA, wc2t, bufB, 256, 256,
                                                               nullptr, nullptr, nullptr, nullptr);
        agg_k<256><<<N_NODES / 4 + 1, 256, 0, stream>>>(bufB, bufA, dinv, offsets, csr, N_NODES);
        // layer 3: hs3 = (relu(a2 + bc2) @ W3) * dinv
        gemm_k<1, 0><<<dim3(M_PAD / 128, 2), 256, 0, stream>>>(bufA, wc3t, bufB, 256, 256,
                                                               bc2, nullptr, dinv, nullptr);
        agg_k<256><<<N_NODES / 4 + 1, 256, 0, stream>>>(bufB, bufA, dinv, offsets, csr, N_NODES);
        // layer 4: hs4 = (relu(a3 + bc3) @ W4) * dinv   K=256 N=128
        gemm_k<1, 0><<<dim3(M_PAD / 128, 1), 256, 0, stream>>>(bufA, wc4t, bufB, 256, 128,
                                                               bc3, nullptr, dinv, nullptr);
        agg_k<128><<<N_NODES / 4 + 1, 256, 0, stream>>>(bufB, bufA, dinv, offsets, csr, N_NODES);

        pool2_k<<<NG / 4, 256, 0, stream>>>(bufA, bc4, gstart, cbuf + t * 128);
    }

    // notes MLPs -> cbuf cols 256..511
    for (int t = 0; t < 2; ++t) {
        const float* nt = t ? nt2 : nt1;
        f2b_pad_k<<<(NG * 128) / 256, 256, 0, stream>>>(nt, notesA, NG * 128, NG * 128);
        gemm_k<0, 1><<<dim3(NG / 128, 2), 256, 0, stream>>>(notesA, wn1t, nh, 128, 256,
                                                            nullptr, nullptr, nullptr, bn1);
        gemm_k<0, 1><<<dim3(NG / 128, 1), 256, 0, stream>>>(nh, wn2t, cbuf + 256 + t * 128, 256, 512,
                                                            nullptr, nullptr, nullptr, bn2);
    }

    // fusion head
    gemm_k<0, 1><<<dim3(NG / 128, 2), 256, 0, stream>>>(cbuf, wf1t, h1, 512, 256,
                                                        nullptr, nullptr, nullptr, bf1);
    hipMemsetAsync(colsum, 0, 2048, stream);
    colred_k<<<256, 256, 0, stream>>>(h1, colsum, colsumsq, 256, 32);
    bnfin_k<<<1, 256, 0, stream>>>(colsum, colsumsq, g1, be1, scale, shift, 256);
    gemm_k<2, 1><<<dim3(NG / 128, 1), 256, 0, stream>>>(h1, wf2t, h2, 256, 128,
                                                        scale, shift, nullptr, bf2);
    hipMemsetAsync(colsum, 0, 2048, stream);
    colred_k<<<128, 128, 0, stream>>>(h2, colsum, colsumsq, 128, 64);
    bnfin_k<<<1, 128, 0, stream>>>(colsum, colsumsq, g2, be2, scale, shift, 128);
    gemm_k<2, 2><<<dim3(NG / 128, 1), 256, 0, stream>>>(h2, wf3t, d_out, 128, 128,
                                                        scale, shift, nullptr, bf3);
}